// Round 1
// baseline (715.623 us; speedup 1.0000x reference)
//
#include <hip/hip_runtime.h>

#define SGRID 128
#define CIN 64
#define TPTS 128     // points per block
#define BLOCK 256

// ---------------- voxel table ----------------
__global__ void init_table(int* table, int n) {
    int i = blockIdx.x * blockDim.x + threadIdx.x;
    int stride = gridDim.x * blockDim.x;
    for (; i < n; i += stride) table[i] = -1;
}

__global__ void scatter_table(const int* __restrict__ coords, int* __restrict__ table, int n) {
    int i = blockIdx.x * blockDim.x + threadIdx.x;
    if (i >= n) return;
    int b = coords[i*4+0], x = coords[i*4+1], y = coords[i*4+2], z = coords[i*4+3];
    int key = ((b * SGRID + x) * SGRID + y) * SGRID + z;
    table[key] = i;
}

// ---------------- sparse conv layer ----------------
// out[n,:] = sum_o feats[nbr(n,o),:] @ W[o]   (64x64 per offset, 27 offsets)
__launch_bounds__(BLOCK, 2)
__global__ void conv_kernel(const float* __restrict__ F, const float* __restrict__ W,
                            float* __restrict__ O, const int* __restrict__ table,
                            const int* __restrict__ coords, int n) {
    __shared__ float sW[64][68];          // [k][c], pad 64->68 (16B-aligned rows)
    __shared__ float sF[64][TPTS + 4];    // [k][p] transposed, stride 132 (16B-aligned)
    __shared__ int   snbr[27][TPTS];

    const int tid = threadIdx.x;
    const int p0  = blockIdx.x * TPTS;

    // ---- neighbor ids for this block's points (once) ----
    for (int idx = tid; idx < 27 * TPTS; idx += BLOCK) {
        int o = idx >> 7;            // idx / 128
        int p = idx & (TPTS - 1);
        int m = -1;
        int g = p0 + p;
        if (g < n) {
            int b = coords[g*4+0], x = coords[g*4+1], y = coords[g*4+2], z = coords[g*4+3];
            int dx = o / 9 - 1, dy = (o / 3) % 3 - 1, dz = o % 3 - 1;
            int qx = x + dx, qy = y + dy, qz = z + dz;
            if (((unsigned)qx < SGRID) && ((unsigned)qy < SGRID) && ((unsigned)qz < SGRID)) {
                int qkey = ((b * SGRID + qx) * SGRID + qy) * SGRID + qz;
                m = table[qkey];
            }
        }
        snbr[o][p] = m;
    }
    __syncthreads();

    const int cg    = tid & 7;   // channel group (8 channels)
    const int pg    = tid >> 3;  // point group (4 points)
    const int cbase = cg * 8;

    float acc[4][8];
    #pragma unroll
    for (int i = 0; i < 4; ++i)
        #pragma unroll
        for (int j = 0; j < 8; ++j) acc[i][j] = 0.f;

    const int prow  = tid >> 1;        // 0..127: which point row this thread stages
    const int khalf = (tid & 1) * 32;  // which half of the 64 channels

    for (int o = 0; o < 27; ++o) {
        // ---- stage W[o] (64x64 fp32 = 1024 float4) ----
        const float4* W4 = (const float4*)(W + o * 64 * 64);
        #pragma unroll
        for (int j = 0; j < 4; ++j) {
            int v  = tid + j * BLOCK;   // 0..1023
            int k  = v >> 4;
            int c4 = v & 15;
            *(float4*)&sW[k][c4 * 4] = W4[v];
        }
        // ---- stage gathered feats transposed: sF[k][p] ----
        {
            int m = snbr[o][prow];
            if (m >= 0) {
                const float4* Fr = (const float4*)(F + m * 64 + khalf);
                #pragma unroll
                for (int j = 0; j < 8; ++j) {
                    float4 v = Fr[j];
                    sF[khalf + j*4 + 0][prow] = v.x;
                    sF[khalf + j*4 + 1][prow] = v.y;
                    sF[khalf + j*4 + 2][prow] = v.z;
                    sF[khalf + j*4 + 3][prow] = v.w;
                }
            } else {
                #pragma unroll
                for (int j = 0; j < 32; ++j) sF[khalf + j][prow] = 0.f;
            }
        }
        __syncthreads();

        // ---- register-tile FMA: 4 points x 8 channels per thread ----
        #pragma unroll 8
        for (int k = 0; k < 64; ++k) {
            float4 f  = *(const float4*)&sF[k][pg * 4];
            float4 w0 = *(const float4*)&sW[k][cbase];
            float4 w1 = *(const float4*)&sW[k][cbase + 4];
            float fv[4] = {f.x, f.y, f.z, f.w};
            float wv[8] = {w0.x, w0.y, w0.z, w0.w, w1.x, w1.y, w1.z, w1.w};
            #pragma unroll
            for (int i = 0; i < 4; ++i)
                #pragma unroll
                for (int j = 0; j < 8; ++j)
                    acc[i][j] += fv[i] * wv[j];
        }
        __syncthreads();
    }

    // ---- write out ----
    #pragma unroll
    for (int i = 0; i < 4; ++i) {
        int g = p0 + pg * 4 + i;
        if (g < n) {
            float4 o0 = {acc[i][0], acc[i][1], acc[i][2], acc[i][3]};
            float4 o1 = {acc[i][4], acc[i][5], acc[i][6], acc[i][7]};
            *(float4*)&O[g * 64 + cbase]     = o0;
            *(float4*)&O[g * 64 + cbase + 4] = o1;
        }
    }
}

extern "C" void kernel_launch(void* const* d_in, const int* in_sizes, int n_in,
                              void* d_out, int out_size, void* d_ws, size_t ws_size,
                              hipStream_t stream) {
    const float* feats  = (const float*)d_in[0];
    const int*   coords = (const int*)d_in[1];
    const float* W1     = (const float*)d_in[2];
    const float* W2     = (const float*)d_in[3];
    float* out = (float*)d_out;

    const int N = in_sizes[0] / CIN;          // 100000
    const int tsize = 2 * SGRID * SGRID * SGRID;  // B * S^3 = 4,194,304

    int*   table = (int*)d_ws;
    float* h     = (float*)((char*)d_ws + (size_t)tsize * sizeof(int));

    init_table<<<2048, 256, 0, stream>>>(table, tsize);
    scatter_table<<<(N + 255) / 256, 256, 0, stream>>>(coords, table, N);

    const int nb = (N + TPTS - 1) / TPTS;
    conv_kernel<<<nb, BLOCK, 0, stream>>>(feats, W1, h,   table, coords, N);
    conv_kernel<<<nb, BLOCK, 0, stream>>>(h,     W2, out, table, coords, N);
}

// Round 2
// 178.957 us; speedup vs baseline: 3.9988x; 3.9988x over previous
//
#include <hip/hip_runtime.h>
#include <stdint.h>

#define SGRID 128
#define BLOCK 256

typedef __bf16 bf16_t;
typedef bf16_t bf16x8 __attribute__((ext_vector_type(8)));
typedef float f32x4 __attribute__((ext_vector_type(4)));

// round-to-nearest-even bf16 split: f ~= hi + lo
static __device__ __forceinline__ void split2(float f, unsigned short& h, unsigned short& l) {
    unsigned u = __float_as_uint(f);
    unsigned hr = (u + 0x7FFFu + ((u >> 16) & 1u)) >> 16;
    h = (unsigned short)hr;
    float fh = __uint_as_float(hr << 16);
    float fl = f - fh;
    unsigned u2 = __float_as_uint(fl);
    l = (unsigned short)((u2 + 0x7FFFu + ((u2 >> 16) & 1u)) >> 16);
}

static __device__ __forceinline__ f32x4 mfma16(uint4 a, uint4 b, f32x4 c) {
    union { uint4 u; bf16x8 v; } ua, ub;
    ua.u = a; ub.u = b;
    return __builtin_amdgcn_mfma_f32_16x16x32_bf16(ua.v, ub.v, c, 0, 0, 0);
}

// ---------------- voxel table ----------------
__global__ void init_table(int* table, int n) {
    int i = blockIdx.x * blockDim.x + threadIdx.x;
    int stride = gridDim.x * blockDim.x;
    for (; i < n; i += stride) table[i] = -1;
}

__global__ void scatter_table(const int* __restrict__ coords, int* __restrict__ table, int n) {
    int i = blockIdx.x * blockDim.x + threadIdx.x;
    if (i >= n) return;
    int b = coords[i*4+0], x = coords[i*4+1], y = coords[i*4+2], z = coords[i*4+3];
    table[((b * SGRID + x) * SGRID + y) * SGRID + z] = i;
}

// ---------------- split feats fp32 -> bf16 hi/lo ----------------
__global__ void split_feats(const float* __restrict__ F, unsigned short* __restrict__ H,
                            unsigned short* __restrict__ L, int nelem) {
    int i = blockIdx.x * blockDim.x + threadIdx.x;
    if (i * 8 >= nelem) return;
    float4 v0 = ((const float4*)F)[i*2];
    float4 v1 = ((const float4*)F)[i*2+1];
    float vv[8] = {v0.x, v0.y, v0.z, v0.w, v1.x, v1.y, v1.z, v1.w};
    unsigned short h[8], l[8];
    #pragma unroll
    for (int j = 0; j < 8; ++j) split2(vv[j], h[j], l[j]);
    uint4 hv, lv;
    hv.x = h[0] | (h[1] << 16); hv.y = h[2] | (h[3] << 16);
    hv.z = h[4] | (h[5] << 16); hv.w = h[6] | (h[7] << 16);
    lv.x = l[0] | (l[1] << 16); lv.y = l[2] | (l[3] << 16);
    lv.z = l[4] | (l[5] << 16); lv.w = l[6] | (l[7] << 16);
    ((uint4*)H)[i] = hv;
    ((uint4*)L)[i] = lv;
}

// ---------------- transpose + split W: [27][cin][cout] f32 -> [27][cout][cin] bf16 hi/lo ----------------
__global__ void prep_w(const float* __restrict__ W, unsigned short* __restrict__ Wh,
                       unsigned short* __restrict__ Wl) {
    int idx = blockIdx.x * blockDim.x + threadIdx.x;
    if (idx >= 27 * 64 * 8) return;
    int ci8 = idx & 7;
    int co  = (idx >> 3) & 63;
    int o   = idx >> 9;
    unsigned short h[8], l[8];
    #pragma unroll
    for (int j = 0; j < 8; ++j) {
        float v = W[((size_t)o * 64 + ci8 * 8 + j) * 64 + co];
        split2(v, h[j], l[j]);
    }
    uint4 hv, lv;
    hv.x = h[0] | (h[1] << 16); hv.y = h[2] | (h[3] << 16);
    hv.z = h[4] | (h[5] << 16); hv.w = h[6] | (h[7] << 16);
    lv.x = l[0] | (l[1] << 16); lv.y = l[2] | (l[3] << 16);
    lv.z = l[4] | (l[5] << 16); lv.w = l[6] | (l[7] << 16);
    size_t d = ((size_t)o * 4096 + co * 64 + ci8 * 8) / 8;  // uint4 index
    ((uint4*)Wh)[d] = hv;
    ((uint4*)Wl)[d] = lv;
}

// ---------------- MFMA sparse conv layer ----------------
// Block: 128 points x 64 cout. 4 waves, each 32 pts x 64 cout.
// acc tiles: [rt=2][ct=4] of 16x16, mfma_f32_16x16x32_bf16, 3-term bf16 split.
__global__ void __launch_bounds__(BLOCK) conv_mfma(
    const unsigned short* __restrict__ Fh, const unsigned short* __restrict__ Fl,
    const unsigned short* __restrict__ Wh, const unsigned short* __restrict__ Wl,
    const int* __restrict__ table, const int* __restrict__ coords,
    float* __restrict__ Of, unsigned short* __restrict__ Oh, unsigned short* __restrict__ Ol,
    int n, int write_split)
{
    __shared__ unsigned short sW[2][4096];   // [hi/lo][co*64+ci], XOR-swizzled 16B granules
    __shared__ int snbr[27][128];

    const int tid = threadIdx.x;
    const int p0  = blockIdx.x * 128;

    // ---- neighbor ids for this block's 128 points ----
    for (int idx = tid; idx < 27 * 128; idx += BLOCK) {
        int o = idx >> 7, p = idx & 127;
        int m = -1, g = p0 + p;
        if (g < n) {
            int4 c4 = ((const int4*)coords)[g];
            int dx = o / 9 - 1, dy = (o / 3) % 3 - 1, dz = o % 3 - 1;
            int qx = c4.y + dx, qy = c4.z + dy, qz = c4.w + dz;
            if ((unsigned)qx < SGRID && (unsigned)qy < SGRID && (unsigned)qz < SGRID)
                m = table[((c4.x * SGRID + qx) * SGRID + qy) * SGRID + qz];
        }
        snbr[o][p] = m;
    }

    const int lane = tid & 63;
    const int wave = tid >> 6;
    const int r    = lane & 15;   // row-in-tile (A) / col-in-tile (B/C)
    const int lq   = lane >> 4;   // quad 0..3

    // hoisted: staging swizzle (write-side). granule g: row=g>>3, slot=g&7 -> slot^(row&7)
    const int g0 = tid, g1 = tid + 256;
    const int sg0 = (g0 & ~7) | ((g0 & 7) ^ ((g0 >> 3) & 7));
    const int sg1 = (g1 & ~7) | ((g1 & 7) ^ ((g1 >> 3) & 7));
    // hoisted: B-frag read offsets (ushort units), same XOR on read side
    int bgo[2][4];
    #pragma unroll
    for (int ks = 0; ks < 2; ++ks)
        #pragma unroll
        for (int ct = 0; ct < 4; ++ct) {
            int co = ct * 16 + r;
            bgo[ks][ct] = (co * 8 + ((ks * 4 + lq) ^ (co & 7))) * 8;
        }

    f32x4 acc[2][4];
    #pragma unroll
    for (int i = 0; i < 2; ++i)
        #pragma unroll
        for (int j = 0; j < 4; ++j) acc[i][j] = (f32x4){0.f, 0.f, 0.f, 0.f};

    __syncthreads();  // snbr ready

    for (int o = 0; o < 27; ++o) {
        // issue W-stage global loads (hi: 2 granules/thread, lo: 2)
        const uint4* wsh = (const uint4*)(Wh + (size_t)o * 4096);
        const uint4* wsl = (const uint4*)(Wl + (size_t)o * 4096);
        uint4 w0 = wsh[g0], w1 = wsh[g1], w2 = wsl[g0], w3 = wsl[g1];

        // issue A-frag gather loads (per-lane 16B, rows = this wave's 32 points)
        uint4 ah[2][2], al[2][2];
        #pragma unroll
        for (int rt = 0; rt < 2; ++rt) {
            int nb = snbr[o][wave * 32 + rt * 16 + r];
            if (nb >= 0) {
                const uint4* fh4 = (const uint4*)(Fh + (size_t)nb * 64 + lq * 8);
                const uint4* fl4 = (const uint4*)(Fl + (size_t)nb * 64 + lq * 8);
                ah[rt][0] = fh4[0]; ah[rt][1] = fh4[4];   // ks*32 elems = 4 uint4
                al[rt][0] = fl4[0]; al[rt][1] = fl4[4];
            } else {
                ah[rt][0] = ah[rt][1] = (uint4){0,0,0,0};
                al[rt][0] = al[rt][1] = (uint4){0,0,0,0};
            }
        }

        __syncthreads();  // previous offset's B-reads done before overwrite
        ((uint4*)&sW[0][0])[sg0] = w0;
        ((uint4*)&sW[0][0])[sg1] = w1;
        ((uint4*)&sW[1][0])[sg0] = w2;
        ((uint4*)&sW[1][0])[sg1] = w3;
        __syncthreads();  // sW ready

        #pragma unroll
        for (int ks = 0; ks < 2; ++ks) {
            uint4 bh[4], bl[4];
            #pragma unroll
            for (int ct = 0; ct < 4; ++ct) {
                bh[ct] = *(const uint4*)&sW[0][bgo[ks][ct]];
                bl[ct] = *(const uint4*)&sW[1][bgo[ks][ct]];
            }
            #pragma unroll
            for (int rt = 0; rt < 2; ++rt)
                #pragma unroll
                for (int ct = 0; ct < 4; ++ct) {
                    acc[rt][ct] = mfma16(ah[rt][ks], bh[ct], acc[rt][ct]);
                    acc[rt][ct] = mfma16(al[rt][ks], bh[ct], acc[rt][ct]);
                    acc[rt][ct] = mfma16(ah[rt][ks], bl[ct], acc[rt][ct]);
                }
        }
    }

    // ---- epilogue: C/D layout col=lane&15, row=(lane>>4)*4+reg ----
    #pragma unroll
    for (int rt = 0; rt < 2; ++rt)
        #pragma unroll
        for (int ct = 0; ct < 4; ++ct)
            #pragma unroll
            for (int j = 0; j < 4; ++j) {
                int g = p0 + wave * 32 + rt * 16 + lq * 4 + j;
                if (g < n) {
                    int col = ct * 16 + r;
                    float v = acc[rt][ct][j];
                    if (write_split) {
                        unsigned short h, l;
                        split2(v, h, l);
                        Oh[(size_t)g * 64 + col] = h;
                        Ol[(size_t)g * 64 + col] = l;
                    } else {
                        Of[(size_t)g * 64 + col] = v;
                    }
                }
            }
}

extern "C" void kernel_launch(void* const* d_in, const int* in_sizes, int n_in,
                              void* d_out, int out_size, void* d_ws, size_t ws_size,
                              hipStream_t stream) {
    const float* feats  = (const float*)d_in[0];
    const int*   coords = (const int*)d_in[1];
    const float* W1     = (const float*)d_in[2];
    const float* W2     = (const float*)d_in[3];
    float* out = (float*)d_out;

    const int N  = in_sizes[0] / 64;
    const int NC = N * 64;
    const size_t tsize = 2ull * SGRID * SGRID * SGRID;  // B * S^3

    char* p = (char*)d_ws;
    int* table = (int*)p;                 p += tsize * 4;
    unsigned short* Fh  = (unsigned short*)p; p += (size_t)NC * 2;
    unsigned short* Fl  = (unsigned short*)p; p += (size_t)NC * 2;
    unsigned short* Hh  = (unsigned short*)p; p += (size_t)NC * 2;
    unsigned short* Hl  = (unsigned short*)p; p += (size_t)NC * 2;
    unsigned short* W1h = (unsigned short*)p; p += 27 * 4096 * 2;
    unsigned short* W1l = (unsigned short*)p; p += 27 * 4096 * 2;
    unsigned short* W2h = (unsigned short*)p; p += 27 * 4096 * 2;
    unsigned short* W2l = (unsigned short*)p; p += 27 * 4096 * 2;

    init_table<<<2048, 256, 0, stream>>>(table, (int)tsize);
    scatter_table<<<(N + 255) / 256, 256, 0, stream>>>(coords, table, N);
    split_feats<<<(NC / 8 + 255) / 256, 256, 0, stream>>>(feats, Fh, Fl, NC);
    prep_w<<<(27 * 64 * 8 + 255) / 256, 256, 0, stream>>>(W1, W1h, W1l);
    prep_w<<<(27 * 64 * 8 + 255) / 256, 256, 0, stream>>>(W2, W2h, W2l);

    const int nb = (N + 127) / 128;
    conv_mfma<<<nb, BLOCK, 0, stream>>>(Fh, Fl, W1h, W1l, table, coords,
                                        nullptr, Hh, Hl, N, 1);
    conv_mfma<<<nb, BLOCK, 0, stream>>>(Hh, Hl, W2h, W2l, table, coords,
                                        out, nullptr, nullptr, N, 0);
}

// Round 3
// 154.610 us; speedup vs baseline: 4.6286x; 1.1575x over previous
//
#include <hip/hip_runtime.h>
#include <stdint.h>

#define SGRID 128

typedef _Float16 f16;
typedef f16 f16x8 __attribute__((ext_vector_type(8)));
typedef float f32x4 __attribute__((ext_vector_type(4)));

static __device__ __forceinline__ f32x4 mfma16(uint4 a, uint4 b, f32x4 c) {
    union { uint4 u; f16x8 v; } ua, ub;
    ua.u = a; ub.u = b;
    return __builtin_amdgcn_mfma_f32_16x16x32_f16(ua.v, ub.v, c, 0, 0, 0);
}

// ---------------- voxel table scatter ----------------
__global__ void scatter_table(const int* __restrict__ coords, int* __restrict__ table, int n) {
    int i = blockIdx.x * blockDim.x + threadIdx.x;
    if (i >= n) return;
    int4 c = ((const int4*)coords)[i];
    table[((c.x * SGRID + c.y) * SGRID + c.z) * SGRID + c.w] = i;
}

// ---------------- rulebook: snbr[o][n] + per-32-group active-offset bitmask ----------------
__global__ void build_rules(const int* __restrict__ coords, const int* __restrict__ table,
                            int* __restrict__ snbr, unsigned* __restrict__ gmask, int N) {
    int o  = blockIdx.y;
    int nn = blockIdx.x * blockDim.x + threadIdx.x;
    int found = -1;
    if (nn < N) {
        int4 c = ((const int4*)coords)[nn];
        int dx = o / 9 - 1, dy = (o / 3) % 3 - 1, dz = o % 3 - 1;
        int qx = c.y + dx, qy = c.z + dy, qz = c.w + dz;
        if ((unsigned)qx < SGRID && (unsigned)qy < SGRID && (unsigned)qz < SGRID)
            found = table[((c.x * SGRID + qx) * SGRID + qy) * SGRID + qz];
        snbr[(size_t)o * N + nn] = found;
    }
    unsigned long long bal = __ballot(found >= 0);
    int lane = threadIdx.x & 63;
    if ((lane == 0 || lane == 32) && nn < N) {
        unsigned bits = (lane == 0) ? (unsigned)bal : (unsigned)(bal >> 32);
        if (bits) atomicOr(&gmask[nn >> 5], 1u << o);
    }
}

// ---------------- split feats fp32 -> f16 hi/lo, row layout [n][fh(64)|fl(64)] ----------------
__global__ void split_feats(const float* __restrict__ F, f16* __restrict__ P, int nelem) {
    int i = blockIdx.x * blockDim.x + threadIdx.x;   // one thread per 8 elems
    if (i * 8 >= nelem) return;
    float4 v0 = ((const float4*)F)[i * 2];
    float4 v1 = ((const float4*)F)[i * 2 + 1];
    float vv[8] = {v0.x, v0.y, v0.z, v0.w, v1.x, v1.y, v1.z, v1.w};
    union { f16 h[8]; uint4 u; } hv, lv;
    #pragma unroll
    for (int j = 0; j < 8; ++j) {
        f16 h = (f16)vv[j];
        hv.h[j] = h;
        lv.h[j] = (f16)(vv[j] - (float)h);
    }
    int n = i >> 3, c = (i & 7) * 8;
    *(uint4*)(P + (size_t)n * 128 + c)      = hv.u;
    *(uint4*)(P + (size_t)n * 128 + 64 + c) = lv.u;
}

// ---------------- W -> f16 (hi only), B-fragment order: [o][ct][ks][lane][8] ----------------
__global__ void prep_w(const float* __restrict__ W, f16* __restrict__ Wp) {
    int idx = blockIdx.x * blockDim.x + threadIdx.x;
    if (idx >= 27 * 4 * 2 * 64) return;
    int lane = idx & 63;
    int ks = (idx >> 6) & 1;
    int ct = (idx >> 7) & 3;
    int o  = idx >> 9;
    int co  = ct * 16 + (lane & 15);
    int ci0 = ks * 32 + (lane >> 4) * 8;
    union { f16 h[8]; uint4 u; } hv;
    #pragma unroll
    for (int j = 0; j < 8; ++j)
        hv.h[j] = (f16)W[((size_t)o * 64 + ci0 + j) * 64 + co];
    ((uint4*)Wp)[idx] = hv.u;
}

// ---------------- sparse conv: per-wave 32 pts x 64 cout, active offsets only ----------------
__global__ void __launch_bounds__(256) conv(
    const f16* __restrict__ Fp, const f16* __restrict__ Wp,
    const int* __restrict__ snbr, const unsigned* __restrict__ gmask,
    float* __restrict__ Of, f16* __restrict__ Op,
    int N, int ngroups, int write_split)
{
    int gw = (blockIdx.x * 256 + threadIdx.x) >> 6;
    if (gw >= ngroups) return;
    const int lane = threadIdx.x & 63;
    const int r  = lane & 15;
    const int lq = lane >> 4;
    const int p0 = gw * 32;
    const unsigned mask = gmask[gw];

    f32x4 acc[2][4];
    #pragma unroll
    for (int i = 0; i < 2; ++i)
        #pragma unroll
        for (int j = 0; j < 4; ++j) acc[i][j] = (f32x4){0.f, 0.f, 0.f, 0.f};

    for (int o = 0; o < 27; ++o) {
        if (!((mask >> o) & 1u)) continue;

        // B fragments: 8 x 1KB coalesced loads (L2-resident)
        const uint4* wb = (const uint4*)Wp + (size_t)o * 512 + lane;
        uint4 b[2][4];   // [ks][ct]
        #pragma unroll
        for (int ct = 0; ct < 4; ++ct)
            #pragma unroll
            for (int ks = 0; ks < 2; ++ks)
                b[ks][ct] = wb[(ct * 2 + ks) * 64];

        // A fragments: conditional per-row gather (16B per lane per frag)
        const int* sn = snbr + (size_t)o * N + p0;
        uint4 ah[2][2], al[2][2];   // [rt][ks]
        #pragma unroll
        for (int rt = 0; rt < 2; ++rt) {
            int row = rt * 16 + r;
            int nb = (p0 + row < N) ? sn[row] : -1;
            if (nb >= 0) {
                const uint4* fa = (const uint4*)(Fp + (size_t)nb * 128);
                ah[rt][0] = fa[lq];      ah[rt][1] = fa[4 + lq];
                al[rt][0] = fa[8 + lq];  al[rt][1] = fa[12 + lq];
            } else {
                ah[rt][0] = ah[rt][1] = (uint4){0,0,0,0};
                al[rt][0] = al[rt][1] = (uint4){0,0,0,0};
            }
        }

        #pragma unroll
        for (int ks = 0; ks < 2; ++ks)
            #pragma unroll
            for (int rt = 0; rt < 2; ++rt)
                #pragma unroll
                for (int ct = 0; ct < 4; ++ct) {
                    acc[rt][ct] = mfma16(ah[rt][ks], b[ks][ct], acc[rt][ct]);
                    acc[rt][ct] = mfma16(al[rt][ks], b[ks][ct], acc[rt][ct]);
                }
    }

    // epilogue: C/D layout col = lane&15, row = lq*4 + reg
    #pragma unroll
    for (int rt = 0; rt < 2; ++rt)
        #pragma unroll
        for (int ct = 0; ct < 4; ++ct)
            #pragma unroll
            for (int j = 0; j < 4; ++j) {
                int row = p0 + rt * 16 + lq * 4 + j;
                if (row < N) {
                    int col = ct * 16 + r;
                    float v = acc[rt][ct][j];
                    if (write_split) {
                        f16 hh = (f16)v;
                        f16 hl = (f16)(v - (float)hh);
                        Op[(size_t)row * 128 + col]      = hh;
                        Op[(size_t)row * 128 + 64 + col] = hl;
                    } else {
                        Of[(size_t)row * 64 + col] = v;
                    }
                }
            }
}

extern "C" void kernel_launch(void* const* d_in, const int* in_sizes, int n_in,
                              void* d_out, int out_size, void* d_ws, size_t ws_size,
                              hipStream_t stream) {
    const float* feats  = (const float*)d_in[0];
    const int*   coords = (const int*)d_in[1];
    const float* W1     = (const float*)d_in[2];
    const float* W2     = (const float*)d_in[3];
    float* out = (float*)d_out;

    const int N = in_sizes[0] / 64;
    const int ngroups = (N + 31) / 32;
    const size_t tsize = 2ull * SGRID * SGRID * SGRID;   // B * S^3 ints

    // workspace layout (regionA: table is dead after build_rules; F1prep overlays it)
    char* p = (char*)d_ws;
    size_t regionA = tsize * 4;
    size_t f1bytes = (size_t)N * 128 * 2;
    if (f1bytes > regionA) regionA = f1bytes;
    int* table = (int*)p;
    f16* F1    = (f16*)p;                 p += regionA;
    int* snbr  = (int*)p;                 p += 27ull * N * 4;
    unsigned* gmask = (unsigned*)p;       p += ((size_t)(ngroups + 63) & ~63ull) * 4;
    f16* Hp    = (f16*)p;                 p += (size_t)N * 128 * 2;
    f16* Wp1   = (f16*)p;                 p += 27ull * 4096 * 2;
    f16* Wp2   = (f16*)p;                 p += 27ull * 4096 * 2;

    hipMemsetAsync(table, 0xFF, tsize * 4, stream);
    hipMemsetAsync(gmask, 0, (size_t)ngroups * 4, stream);

    scatter_table<<<(N + 255) / 256, 256, 0, stream>>>(coords, table, N);
    build_rules<<<dim3((N + 255) / 256, 27), 256, 0, stream>>>(coords, table, snbr, gmask, N);
    // table dead from here; F1 overlays it
    split_feats<<<((N * 64 / 8) + 255) / 256, 256, 0, stream>>>(feats, F1, N * 64);
    prep_w<<<(27 * 4 * 2 * 64 + 255) / 256, 256, 0, stream>>>(W1, Wp1);
    prep_w<<<(27 * 4 * 2 * 64 + 255) / 256, 256, 0, stream>>>(W2, Wp2);

    const int nb = (ngroups + 3) / 4;   // 4 waves (groups) per 256-thread block
    conv<<<nb, 256, 0, stream>>>(F1, Wp1, snbr, gmask, nullptr, Hp, N, ngroups, 1);
    conv<<<nb, 256, 0, stream>>>(Hp, Wp2, snbr, gmask, out, nullptr, N, ngroups, 0);
}